// Round 15
// baseline (515.626 us; speedup 1.0000x reference)
//
#include <hip/hip_runtime.h>

typedef _Float16 half8 __attribute__((ext_vector_type(8)));
typedef __fp16  fp16x2 __attribute__((ext_vector_type(2)));
typedef float f32x16 __attribute__((ext_vector_type(16)));

#define M_TRAIN 50000
#define NQ 4096
#define KNN 31

#define LO_SCALE 1024.0f
#define LO_INV   9.765625e-4f

// ---------------------------------------------------------------------------
// Weight prep: fp32 -> fp16 hi/lo (lo scaled x1024), B-fragment-major for
// mfma_f32_32x32x16_f16. Wp[ks][nt][lane][j] <- W[ks*16+(lane>>5)*8+j][nt*32+(lane&31)]
// W0: K padded to 272 (rows 256=y, 257=ind, 258..271 = 0). W1/W2: K=256.
// ---------------------------------------------------------------------------
__global__ void prep_weights_k(const float* __restrict__ W0,
                               const float* __restrict__ W1,
                               const float* __restrict__ W2,
                               _Float16* __restrict__ W0hi, _Float16* __restrict__ W0lo,
                               _Float16* __restrict__ W1hi, _Float16* __restrict__ W1lo,
                               _Float16* __restrict__ W2hi, _Float16* __restrict__ W2lo) {
    int t = blockIdx.x * 256 + threadIdx.x;
    const int n0 = 17 * 8 * 64, n1 = 16 * 8 * 64, n2 = 16 * 8 * 64;
    if (t >= n0 + n1 + n2) return;
    const float* src; _Float16 *dhi, *dlo; int idx, Kin;
    if (t < n0)           { src = W0; dhi = W0hi; dlo = W0lo; idx = t;           Kin = 258; }
    else if (t < n0 + n1) { src = W1; dhi = W1hi; dlo = W1lo; idx = t - n0;      Kin = 256; }
    else                  { src = W2; dhi = W2hi; dlo = W2lo; idx = t - n0 - n1; Kin = 256; }
    int lane = idx & 63, nt = (idx >> 6) & 7, ks = idx >> 9;
    int col = nt * 32 + (lane & 31);
    int k0  = ks * 16 + (lane >> 5) * 8;
    _Float16 vhi[8], vlo[8];
#pragma unroll
    for (int j = 0; j < 8; j++) {
        int k = k0 + j;
        float w = (k < Kin) ? src[k * 256 + col] : 0.f;
        _Float16 hi = (_Float16)w;
        vhi[j] = hi;
        vlo[j] = (_Float16)((w - (float)hi) * LO_SCALE);
    }
    *reinterpret_cast<uint4*>(dhi + (size_t)idx * 8) = *reinterpret_cast<const uint4*>(vhi);
    *reinterpret_cast<uint4*>(dlo + (size_t)idx * 8) = *reinterpret_cast<const uint4*>(vlo);
}

// ---------------------------------------------------------------------------
// kNN: exact top-31 under float64 ordering, ties -> lower index.
// Double-buffered LDS tiles, ONE barrier per tile: write staged regs ->
// buf[cur], issue next tile's loads to regs, barrier, scan. Load latency
// overlaps barrier-wait + scan. Selection math identical to R12 (bit-exact).
// ---------------------------------------------------------------------------
#define QPB2 4
#define TILE2 2048
#define CAP2 128

__global__ __launch_bounds__(256) void knn_k(const float* __restrict__ qs,
                                             const float* __restrict__ ts,
                                             int* __restrict__ nb) {
    __shared__ __align__(16) float tile[2][TILE2 * 2];   // 32 KB double buffer
    __shared__ float  mrg[QPB2][128];
    __shared__ int    ci[QPB2][CAP2];
    __shared__ double chd[QPB2][CAP2];
    __shared__ int    cnt[QPB2];

    const int t = threadIdx.x;
    const int w = t >> 6, lane = t & 63;
    const int q = blockIdx.x * QPB2 + w;

    if (lane == 0) cnt[w] = 0;
    const float qx = qs[q * 2 + 0], qy = qs[q * 2 + 1];
    const float4* tsv = reinterpret_cast<const float4*>(ts);

    float4 stg[4];
    // ---- pass 1: per-lane top-2, double-buffered staging ----
    {
        int nf4 = TILE2 / 2;
#pragma unroll
        for (int j = 0; j < 4; j++) { int i = t + 256 * j; if (i < nf4) stg[j] = tsv[i]; }
    }
    float v0 = 3.4e38f, v1 = 3.4e38f;
    int cur = 0;
    for (int base = 0; base < M_TRAIN; base += TILE2) {
        const int n = min(TILE2, M_TRAIN - base);
        const int nf4 = n / 2;
#pragma unroll
        for (int j = 0; j < 4; j++) {
            int i = t + 256 * j;
            if (i < nf4) reinterpret_cast<float4*>(tile[cur])[i] = stg[j];
        }
        const int nbase = base + TILE2;
        if (nbase < M_TRAIN) {
            int nn4 = min(TILE2, M_TRAIN - nbase) / 2;
#pragma unroll
            for (int j = 0; j < 4; j++) {
                int i = t + 256 * j;
                if (i < nn4) stg[j] = tsv[(size_t)nbase / 2 + i];
            }
        }
        __syncthreads();
        const float2* tv = reinterpret_cast<const float2*>(tile[cur]);
#pragma unroll 4
        for (int p = lane; p < n; p += 64) {
            float2 pt = tv[p];
            float dx = qx - pt.x, dy = qy - pt.y;
            float d2 = fmaf(dx, dx, dy * dy);
            v1 = fminf(v1, fmaxf(v0, d2));
            v0 = fminf(v0, d2);
        }
        cur ^= 1;
    }
    mrg[w][2 * lane]     = v0;
    mrg[w][2 * lane + 1] = v1;
    __syncthreads();   // also fences pass-1 scans vs pass-2 buffer writes

    // ---- 31st smallest of the 128 merged values -> collection threshold ----
    float xa = mrg[w][lane], xb = mrg[w][64 + lane];
    int lea = 0, leb = 0;
    for (int i = 0; i < 128; i++) {
        float v = mrg[w][i];              // broadcast read, conflict-free
        lea += (v <= xa) ? 1 : 0;
        leb += (v <= xb) ? 1 : 0;
    }
    float tc = 3.4e38f;
    if (lea >= 31) tc = xa;
    if (leb >= 31 && xb < tc) tc = xb;
#pragma unroll
    for (int off = 32; off; off >>= 1)
        tc = fminf(tc, __shfl_xor(tc, off));
    const float thr = tc * 1.00001f + 1e-7f;   // covers f32-vs-f64 key noise

    // ---- pass 2: collect candidate indices (same double-buffer scheme) ----
    {
        int nf4 = TILE2 / 2;
#pragma unroll
        for (int j = 0; j < 4; j++) { int i = t + 256 * j; if (i < nf4) stg[j] = tsv[i]; }
    }
    cur = 0;
    for (int base = 0; base < M_TRAIN; base += TILE2) {
        const int n = min(TILE2, M_TRAIN - base);
        const int nf4 = n / 2;
#pragma unroll
        for (int j = 0; j < 4; j++) {
            int i = t + 256 * j;
            if (i < nf4) reinterpret_cast<float4*>(tile[cur])[i] = stg[j];
        }
        const int nbase = base + TILE2;
        if (nbase < M_TRAIN) {
            int nn4 = min(TILE2, M_TRAIN - nbase) / 2;
#pragma unroll
            for (int j = 0; j < 4; j++) {
                int i = t + 256 * j;
                if (i < nn4) stg[j] = tsv[(size_t)nbase / 2 + i];
            }
        }
        __syncthreads();
        const float2* tv = reinterpret_cast<const float2*>(tile[cur]);
#pragma unroll 4
        for (int p = lane; p < n; p += 64) {
            float2 pt = tv[p];
            float dx = qx - pt.x, dy = qy - pt.y;
            float d2 = fmaf(dx, dx, dy * dy);
            if (d2 < thr) {
                int pos = atomicAdd(&cnt[w], 1);
                if (pos < CAP2) ci[w][pos] = base + p;
            }
        }
        cur ^= 1;
    }
    __syncthreads();

    // ---- pass 3: exact float64 rank among candidates, ties -> lower index ----
    const int C = min(cnt[w], CAP2);
    for (int c = lane; c < C; c += 64) {
        int idx = ci[w][c];
        double dx = (double)qx - (double)ts[idx * 2];
        double dy = (double)qy - (double)ts[idx * 2 + 1];
        chd[w][c] = dx * dx + dy * dy;
    }
    __syncthreads();
    for (int c = lane; c < C; c += 64) {
        double key = chd[w][c];
        int   idx = ci[w][c];
        int rank = 0;
        for (int o = 0; o < C; o++) {
            double ok = chd[w][o];
            int    oi = ci[w][o];
            rank += ((ok < key) || (ok == key && oi < idx)) ? 1 : 0;
        }
        if (rank < KNN) nb[q * KNN + rank] = idx;
    }
}

// ---------------------------------------------------------------------------
// Fused graph build + 3-layer GCN + head. 2 graphs (64 rows) per block,
// 512 threads / 8 waves (best-measured R12/R13 shape, ~195 us); each wave
// owns 32 output cols for BOTH graphs. fp16 hi/lo split MFMA; T^T in
// registers (shfl_xor half-exchange). LDS 81,152 B -> 2 blocks/CU.
// ---------------------------------------------------------------------------
#define PX 276   // X/H row pitch in fp16 (552B stride -> 2-way-free b64 reads)
#define PT 36    // Ahat row pitch in fp16

__device__ inline half8 ld_h8(const _Float16* p) {   // LDS, 8B aligned
    union { half8 h; uint2 u[2]; } r;
    r.u[0] = *reinterpret_cast<const uint2*>(p);
    r.u[1] = *reinterpret_cast<const uint2*>(p + 4);
    return r.h;
}
__device__ inline half8 ld_h8_g(const _Float16* p) { // global, 16B aligned
    union { half8 h; uint4 u; } r;
    r.u = *reinterpret_cast<const uint4*>(p);
    return r.h;
}
__device__ inline f32x16 zero16() {
    f32x16 z;
#pragma unroll
    for (int i = 0; i < 16; i++) z[i] = 0.f;
    return z;
}
__device__ inline unsigned pk_u(float a, float b) {   // packed f16 (RTZ), 1 inst
    union { fp16x2 v; unsigned u; } c;
    c.v = __builtin_amdgcn_cvt_pkrtz(a, b);
    return c.u;
}
__device__ inline float f16lo(unsigned u) {
    union { unsigned u; fp16x2 v; } c; c.u = u; return (float)c.v[0];
}
__device__ inline float f16hi(unsigned u) {
    union { unsigned u; fp16x2 v; } c; c.u = u; return (float)c.v[1];
}
// Build apply A-fragment (nodes 16*ks2 + 8h + j) from register-resident packed
// T^T words w[8] (word g = slots 2g,2g+1; slot r holds node (r&3)+8(r>>2)+4h).
__device__ inline half8 frag_x(const unsigned* w, int ks2, int h) {
    unsigned w0 = w[4 * ks2 + 0], w1 = w[4 * ks2 + 1];
    unsigned w2 = w[4 * ks2 + 2], w3 = w[4 * ks2 + 3];
    unsigned sA = h ? w0 : w2, sB = h ? w1 : w3;      // what partner needs
    unsigned rA = __shfl_xor(sA, 32);
    unsigned rB = __shfl_xor(sB, 32);
    unsigned kA = h ? w2 : w0, kB = h ? w3 : w1;      // what we keep
    union { half8 h8; unsigned u[4]; } f;
    f.u[0] = h ? rA : kA;
    f.u[1] = h ? rB : kB;
    f.u[2] = h ? kA : rA;
    f.u[3] = h ? kB : rB;
    return f.h8;
}
#define MFMA(a, b, c) __builtin_amdgcn_mfma_f32_32x32x16_f16((a), (b), (c), 0, 0, 0)

__global__ __launch_bounds__(512, 4) void gcn_k(
    const float* __restrict__ qs, const float* __restrict__ qf,
    const float* __restrict__ ts, const float* __restrict__ tf,
    const float* __restrict__ ty, const float* __restrict__ Wout,
    const int* __restrict__ nb,
    const _Float16* __restrict__ W0hi, const _Float16* __restrict__ W0lo,
    const _Float16* __restrict__ W1hi, const _Float16* __restrict__ W1lo,
    const _Float16* __restrict__ W2hi, const _Float16* __restrict__ W2lo,
    float* __restrict__ out) {
    __shared__ __align__(16) _Float16 Xhi[64 * PX];   // 35,328 B
    __shared__ __align__(16) _Float16 Xlo[64 * PX];   // 35,328 B
    __shared__ _Float16 Ahhi[2 * 32 * PT];            //  4,608 B
    __shared__ _Float16 Ahlo[2 * 32 * PT];            //  4,608 B
    __shared__ float coords[128];
    __shared__ float dinv[64];
    __shared__ float yvs[64];
    __shared__ int   idxs[64];

    const int t = threadIdx.x;
    const int w = t >> 6, lane = t & 63;
    const int h = lane >> 5, ln = lane & 31;
    const int g2 = blockIdx.x * 2;          // first graph of this block

    // ---- indices, coords, y values (64 nodes = 2 graphs) ----
    if (t < 64) {
        int g = t >> 5, n = t & 31;
        int idx = (n == 0) ? -1 : nb[(g2 + g) * KNN + (n - 1)];
        idxs[t] = idx;
        const float* c = (n == 0) ? (qs + (size_t)(g2 + g) * 2) : (ts + (size_t)idx * 2);
        coords[t * 2 + 0] = c[0];
        coords[t * 2 + 1] = c[1];
        yvs[t] = (n == 0) ? 0.f : ty[idx];
    }
    __syncthreads();

    // ---- build X hi/lo: 64 rows, 8 rows per wave, prefetched gathers ----
    {
        const float* s0 = ((w & 31) == 0) ? (qf + (size_t)(g2 + (w >> 5)) * 256)
                                          : (tf + (size_t)idxs[w] * 256);
        float4 pv = reinterpret_cast<const float4*>(s0)[lane];
        for (int r = w; r < 64; r += 8) {
            float4 cv = pv;
            int rn = r + 8;
            if (rn < 64) {
                const float* sn = ((rn & 31) == 0) ? (qf + (size_t)(g2 + (rn >> 5)) * 256)
                                                   : (tf + (size_t)idxs[rn] * 256);
                pv = reinterpret_cast<const float4*>(sn)[lane];
            }
            float a4[4] = {cv.x, cv.y, cv.z, cv.w};
            unsigned hw[2], lw[2];
#pragma unroll
            for (int j = 0; j < 2; j++) {
                float x0 = a4[2 * j], x1 = a4[2 * j + 1];
                hw[j] = pk_u(x0, x1);
                lw[j] = pk_u((x0 - f16lo(hw[j])) * LO_SCALE,
                             (x1 - f16hi(hw[j])) * LO_SCALE);
            }
            *reinterpret_cast<uint2*>(&Xhi[r * PX + 4 * lane]) = *reinterpret_cast<uint2*>(hw);
            *reinterpret_cast<uint2*>(&Xlo[r * PX + 4 * lane]) = *reinterpret_cast<uint2*>(lw);
            if (lane == 0) {   // K-tail cols 256..271: y, ind, zeros
                float yv = yvs[r];
                _Float16 thi[16], tlo[16];
#pragma unroll
                for (int j = 0; j < 16; j++) { thi[j] = (_Float16)0.f; tlo[j] = (_Float16)0.f; }
                _Float16 yh = (_Float16)yv;
                thi[0] = yh;
                tlo[0] = (_Float16)((yv - (float)yh) * LO_SCALE);
                thi[1] = ((r & 31) == 0) ? (_Float16)1.f : (_Float16)0.f;
#pragma unroll
                for (int c = 0; c < 4; c++) {
                    *reinterpret_cast<uint2*>(&Xhi[r * PX + 256 + 4 * c]) = reinterpret_cast<uint2*>(thi)[c];
                    *reinterpret_cast<uint2*>(&Xlo[r * PX + 256 + 4 * c]) = reinterpret_cast<uint2*>(tlo)[c];
                }
            }
        }
    }

    // ---- Ahat stage 1: row sums -> dinv (128 threads = 2 graphs) ----
    if (t < 128) {
        int g = t >> 6, i = (t >> 1) & 31, jh = t & 1;
        int ni = g * 32 + i;
        float xi = coords[ni * 2], yi = coords[ni * 2 + 1];
        float part = 0.f;
#pragma unroll
        for (int jj = 0; jj < 16; jj++) {
            int nj = g * 32 + jh * 16 + jj;
            float dx = xi - coords[nj * 2], dy = yi - coords[nj * 2 + 1];
            part += __expf(-0.5f * (dx * dx + dy * dy));
        }
        float asum = part + __shfl_xor(part, 1);
        if (jh == 0) dinv[ni] = 1.0f / sqrtf(asum);
    }
    __syncthreads();
    // ---- Ahat stage 2: normalize in fp32, split hi/lo ----
    if (t < 128) {
        int g = t >> 6, i = (t >> 1) & 31, jh = t & 1;
        int ni = g * 32 + i;
        float xi = coords[ni * 2], yi = coords[ni * 2 + 1];
        float di = dinv[ni];
        _Float16 ahi[16], alo[16];
#pragma unroll
        for (int jj = 0; jj < 16; jj++) {
            int nj = g * 32 + jh * 16 + jj;
            float dx = xi - coords[nj * 2], dy = yi - coords[nj * 2 + 1];
            float a = __expf(-0.5f * (dx * dx + dy * dy)) * di * dinv[nj];
            _Float16 hi = (_Float16)a;
            ahi[jj] = hi;
            alo[jj] = (_Float16)((a - (float)hi) * LO_SCALE);
        }
        _Float16* dh = &Ahhi[ni * PT + jh * 16];
        _Float16* dl = &Ahlo[ni * PT + jh * 16];
#pragma unroll
        for (int c = 0; c < 4; c++) {
            reinterpret_cast<uint2*>(dh)[c] = reinterpret_cast<uint2*>(ahi)[c];
            reinterpret_cast<uint2*>(dl)[c] = reinterpret_cast<uint2*>(alo)[c];
        }
    }
    __syncthreads();

    // ---- 3 GCN layers (wave w: cols [32w,32w+32), BOTH graphs) ----
    const _Float16* Whis[3] = {W0hi, W1hi, W2hi};
    const _Float16* Wlos[3] = {W0lo, W1lo, W2lo};
    for (int layer = 0; layer < 3; layer++) {
        const _Float16* Whi = Whis[layer];
        const _Float16* Wlo = Wlos[layer];
        const int KS = (layer == 0) ? 17 : 16;

        f32x16 acc0 = zero16(), cor0 = zero16();   // graph 0
        f32x16 acc1 = zero16(), cor1 = zero16();   // graph 1
        const int boBase = (w * 64 + lane) * 8;
        const _Float16* Xa0 = &Xhi[ln * PX + 8 * h];
        const _Float16* Xb0 = &Xlo[ln * PX + 8 * h];
        const _Float16* Xa1 = &Xhi[(32 + ln) * PX + 8 * h];
        const _Float16* Xb1 = &Xlo[(32 + ln) * PX + 8 * h];
#pragma unroll 4
        for (int ks = 0; ks < KS; ks++) {
            int bo = boBase + ks * 4096;
            half8 Bh = ld_h8_g(Whi + bo);
            half8 Bl = ld_h8_g(Wlo + bo);
            half8 A0h = ld_h8(Xa0 + ks * 16);
            half8 A0l = ld_h8(Xb0 + ks * 16);
            half8 A1h = ld_h8(Xa1 + ks * 16);
            half8 A1l = ld_h8(Xb1 + ks * 16);
            acc0 = MFMA(A0h, Bh, acc0);
            cor0 = MFMA(A0l, Bh, cor0);
            cor0 = MFMA(A0h, Bl, cor0);
            acc1 = MFMA(A1h, Bh, acc1);
            cor1 = MFMA(A1l, Bh, cor1);
            cor1 = MFMA(A1h, Bl, cor1);
        }
        __syncthreads();   // all waves' GEMM X-reads done (X may be overwritten)

        // ---- T^T in registers: pack f16 hi/lo words (pkrtz) ----
        unsigned whi0[8], wlo0[8], whi1[8], wlo1[8];
#pragma unroll
        for (int g = 0; g < 8; g++) {
            float x0 = fmaf(cor0[2 * g],     LO_INV, acc0[2 * g]);
            float x1 = fmaf(cor0[2 * g + 1], LO_INV, acc0[2 * g + 1]);
            unsigned hw = pk_u(x0, x1);
            whi0[g] = hw;
            wlo0[g] = pk_u((x0 - f16lo(hw)) * LO_SCALE, (x1 - f16hi(hw)) * LO_SCALE);
            float y0 = fmaf(cor1[2 * g],     LO_INV, acc1[2 * g]);
            float y1 = fmaf(cor1[2 * g + 1], LO_INV, acc1[2 * g + 1]);
            unsigned hv = pk_u(y0, y1);
            whi1[g] = hv;
            wlo1[g] = pk_u((y0 - f16lo(hv)) * LO_SCALE, (y1 - f16hi(hv)) * LO_SCALE);
        }

        // ---- apply: OUT^T = T^T * Ahat_g (symmetric); T frags via shfl ----
        f32x16 p0 = zero16(), pc0 = zero16();
        f32x16 p1 = zero16(), pc1 = zero16();
#pragma unroll
        for (int ks2 = 0; ks2 < 2; ks2++) {
            half8 bA0h = ld_h8(&Ahhi[ln * PT + ks2 * 16 + 8 * h]);
            half8 bA0l = ld_h8(&Ahlo[ln * PT + ks2 * 16 + 8 * h]);
            half8 bA1h = ld_h8(&Ahhi[(32 + ln) * PT + ks2 * 16 + 8 * h]);
            half8 bA1l = ld_h8(&Ahlo[(32 + ln) * PT + ks2 * 16 + 8 * h]);
            half8 t0hi = frag_x(whi0, ks2, h);
            half8 t0lo = frag_x(wlo0, ks2, h);
            half8 t1hi = frag_x(whi1, ks2, h);
            half8 t1lo = frag_x(wlo1, ks2, h);
            p0  = MFMA(t0hi, bA0h, p0);
            pc0 = MFMA(t0lo, bA0h, pc0);
            pc0 = MFMA(t0hi, bA0l, pc0);
            p1  = MFMA(t1hi, bA1h, p1);
            pc1 = MFMA(t1lo, bA1h, pc1);
            pc1 = MFMA(t1hi, bA1l, pc1);
        }

        // relu + store H hi/lo (row = g*32+ln, feat = 32w + 8c + 4h + m)
#pragma unroll
        for (int g = 0; g < 2; g++) {
            const f32x16& P = g ? p1 : p0;
            const f32x16& C = g ? pc1 : pc0;
            int row = g * 32 + ln;
#pragma unroll
            for (int c = 0; c < 4; c++) {
                float x0 = fmaf(C[4 * c + 0], LO_INV, P[4 * c + 0]);
                float x1 = fmaf(C[4 * c + 1], LO_INV, P[4 * c + 1]);
                float x2 = fmaf(C[4 * c + 2], LO_INV, P[4 * c + 2]);
                float x3 = fmaf(C[4 * c + 3], LO_INV, P[4 * c + 3]);
                x0 = fmaxf(x0, 0.f); x1 = fmaxf(x1, 0.f);
                x2 = fmaxf(x2, 0.f); x3 = fmaxf(x3, 0.f);
                unsigned hw[2], lw[2];
                hw[0] = pk_u(x0, x1);
                hw[1] = pk_u(x2, x3);
                lw[0] = pk_u((x0 - f16lo(hw[0])) * LO_SCALE, (x1 - f16hi(hw[0])) * LO_SCALE);
                lw[1] = pk_u((x2 - f16lo(hw[1])) * LO_SCALE, (x3 - f16hi(hw[1])) * LO_SCALE);
                int feat = 32 * w + 8 * c + 4 * h;
                *reinterpret_cast<uint2*>(&Xhi[row * PX + feat]) = *reinterpret_cast<uint2*>(hw);
                *reinterpret_cast<uint2*>(&Xlo[row * PX + feat]) = *reinterpret_cast<uint2*>(lw);
            }
        }
        __syncthreads();   // H ready
    }

    // ---- head: out[g2+g] = (Hhi + Hlo/1024)[center_g] . Wout, fp32 ----
    if (w < 2) {
        float4 wv = reinterpret_cast<const float4*>(Wout)[lane];
        union { uint2 u; _Float16 f[4]; } hh, hl;
        hh.u = *reinterpret_cast<const uint2*>(&Xhi[(w * 32) * PX + 4 * lane]);
        hl.u = *reinterpret_cast<const uint2*>(&Xlo[(w * 32) * PX + 4 * lane]);
        float s = ((float)hh.f[0] + (float)hl.f[0] * LO_INV) * wv.x
                + ((float)hh.f[1] + (float)hl.f[1] * LO_INV) * wv.y
                + ((float)hh.f[2] + (float)hl.f[2] * LO_INV) * wv.z
                + ((float)hh.f[3] + (float)hl.f[3] * LO_INV) * wv.w;
#pragma unroll
        for (int off = 32; off; off >>= 1) s += __shfl_xor(s, off);
        if (lane == 0) out[g2 + w] = s;
    }
}

// ---------------------------------------------------------------------------
extern "C" void kernel_launch(void* const* d_in, const int* in_sizes, int n_in,
                              void* d_out, int out_size, void* d_ws, size_t ws_size,
                              hipStream_t stream) {
    const float* qs   = (const float*)d_in[0];
    const float* qf   = (const float*)d_in[1];
    const float* ts   = (const float*)d_in[2];
    const float* tf   = (const float*)d_in[3];
    const float* ty   = (const float*)d_in[4];
    const float* W0   = (const float*)d_in[5];
    const float* W1   = (const float*)d_in[6];
    const float* W2   = (const float*)d_in[7];
    const float* Wout = (const float*)d_in[8];
    float* out = (float*)d_out;

    char* ws = (char*)d_ws;
    int*      nb   = (int*)ws;                         // 507,904 B
    _Float16* W0hi = (_Float16*)(ws + 524288);         // 139,264 B
    _Float16* W0lo = (_Float16*)(ws + 663552);         // 139,264 B
    _Float16* W1hi = (_Float16*)(ws + 802816);         // 131,072 B
    _Float16* W1lo = (_Float16*)(ws + 933888);         // 131,072 B
    _Float16* W2hi = (_Float16*)(ws + 1064960);        // 131,072 B
    _Float16* W2lo = (_Float16*)(ws + 1196032);        // 131,072 B

    hipLaunchKernelGGL(prep_weights_k, dim3(98), dim3(256), 0, stream,
                       W0, W1, W2, W0hi, W0lo, W1hi, W1lo, W2hi, W2lo);
    hipLaunchKernelGGL(knn_k, dim3(NQ / QPB2), dim3(256), 0, stream, qs, ts, nb);
    hipLaunchKernelGGL(gcn_k, dim3(NQ / 2), dim3(512), 0, stream,
                       qs, qf, ts, tf, ty, Wout, nb,
                       W0hi, W0lo, W1hi, W1lo, W2hi, W2lo, out);
}

// Round 16
// 315.781 us; speedup vs baseline: 1.6329x; 1.6329x over previous
//
#include <hip/hip_runtime.h>

typedef _Float16 half8 __attribute__((ext_vector_type(8)));
typedef __fp16  fp16x2 __attribute__((ext_vector_type(2)));
typedef float f32x16 __attribute__((ext_vector_type(16)));

#define M_TRAIN 50000
#define NQ 4096
#define KNN 31

#define LO_SCALE 1024.0f
#define LO_INV   9.765625e-4f

// ---------------------------------------------------------------------------
// Weight prep: fp32 -> fp16 hi/lo (lo scaled x1024), B-fragment-major for
// mfma_f32_32x32x16_f16. Wp[ks][nt][lane][j] <- W[ks*16+(lane>>5)*8+j][nt*32+(lane&31)]
// W0: K padded to 272 (rows 256=y, 257=ind, 258..271 = 0). W1/W2: K=256.
// ---------------------------------------------------------------------------
__global__ void prep_weights_k(const float* __restrict__ W0,
                               const float* __restrict__ W1,
                               const float* __restrict__ W2,
                               _Float16* __restrict__ W0hi, _Float16* __restrict__ W0lo,
                               _Float16* __restrict__ W1hi, _Float16* __restrict__ W1lo,
                               _Float16* __restrict__ W2hi, _Float16* __restrict__ W2lo) {
    int t = blockIdx.x * 256 + threadIdx.x;
    const int n0 = 17 * 8 * 64, n1 = 16 * 8 * 64, n2 = 16 * 8 * 64;
    if (t >= n0 + n1 + n2) return;
    const float* src; _Float16 *dhi, *dlo; int idx, Kin;
    if (t < n0)           { src = W0; dhi = W0hi; dlo = W0lo; idx = t;           Kin = 258; }
    else if (t < n0 + n1) { src = W1; dhi = W1hi; dlo = W1lo; idx = t - n0;      Kin = 256; }
    else                  { src = W2; dhi = W2hi; dlo = W2lo; idx = t - n0 - n1; Kin = 256; }
    int lane = idx & 63, nt = (idx >> 6) & 7, ks = idx >> 9;
    int col = nt * 32 + (lane & 31);
    int k0  = ks * 16 + (lane >> 5) * 8;
    _Float16 vhi[8], vlo[8];
#pragma unroll
    for (int j = 0; j < 8; j++) {
        int k = k0 + j;
        float w = (k < Kin) ? src[k * 256 + col] : 0.f;
        _Float16 hi = (_Float16)w;
        vhi[j] = hi;
        vlo[j] = (_Float16)((w - (float)hi) * LO_SCALE);
    }
    *reinterpret_cast<uint4*>(dhi + (size_t)idx * 8) = *reinterpret_cast<const uint4*>(vhi);
    *reinterpret_cast<uint4*>(dlo + (size_t)idx * 8) = *reinterpret_cast<const uint4*>(vlo);
}

// ---------------------------------------------------------------------------
// kNN: exact top-31 under float64 ordering, ties -> lower index.
// (R12-measured config: QPB2=4, TILE2=2048, simple staging, ~110 us)
// ---------------------------------------------------------------------------
#define QPB2 4
#define TILE2 2048
#define CAP2 128

__global__ __launch_bounds__(256) void knn_k(const float* __restrict__ qs,
                                             const float* __restrict__ ts,
                                             int* __restrict__ nb) {
    __shared__ __align__(16) float tile[TILE2 * 2];   // 16 KB point staging
    __shared__ float  mrg[QPB2][128];
    __shared__ int    ci[QPB2][CAP2];
    __shared__ double chd[QPB2][CAP2];
    __shared__ int    cnt[QPB2];

    const int t = threadIdx.x;
    const int w = t >> 6, lane = t & 63;
    const int q = blockIdx.x * QPB2 + w;

    if (lane == 0) cnt[w] = 0;
    const float qx = qs[q * 2 + 0], qy = qs[q * 2 + 1];
    const float2* tilev = reinterpret_cast<const float2*>(tile);

    // ---- pass 1: per-lane top-2 scan (registers only, branch-free) ----
    float v0 = 3.4e38f, v1 = 3.4e38f;
    for (int base = 0; base < M_TRAIN; base += TILE2) {
        const int n = min(TILE2, M_TRAIN - base);
        __syncthreads();
        for (int i = t; i < n / 2; i += 256)
            reinterpret_cast<float4*>(tile)[i] =
                reinterpret_cast<const float4*>(ts + (size_t)base * 2)[i];
        __syncthreads();
#pragma unroll 4
        for (int p = lane; p < n; p += 64) {
            float2 pt = tilev[p];
            float dx = qx - pt.x, dy = qy - pt.y;
            float d2 = fmaf(dx, dx, dy * dy);
            v1 = fminf(v1, fmaxf(v0, d2));
            v0 = fminf(v0, d2);
        }
    }
    __syncthreads();
    mrg[w][2 * lane]     = v0;
    mrg[w][2 * lane + 1] = v1;
    __syncthreads();

    // ---- 31st smallest of the 128 merged values -> collection threshold ----
    float xa = mrg[w][lane], xb = mrg[w][64 + lane];
    int lea = 0, leb = 0;
    for (int i = 0; i < 128; i++) {
        float v = mrg[w][i];              // broadcast read, conflict-free
        lea += (v <= xa) ? 1 : 0;
        leb += (v <= xb) ? 1 : 0;
    }
    float tc = 3.4e38f;
    if (lea >= 31) tc = xa;
    if (leb >= 31 && xb < tc) tc = xb;
#pragma unroll
    for (int off = 32; off; off >>= 1)
        tc = fminf(tc, __shfl_xor(tc, off));
    const float thr = tc * 1.00001f + 1e-7f;   // covers f32-vs-f64 key noise

    // ---- pass 2: collect candidate indices ----
    for (int base = 0; base < M_TRAIN; base += TILE2) {
        const int n = min(TILE2, M_TRAIN - base);
        __syncthreads();
        for (int i = t; i < n / 2; i += 256)
            reinterpret_cast<float4*>(tile)[i] =
                reinterpret_cast<const float4*>(ts + (size_t)base * 2)[i];
        __syncthreads();
#pragma unroll 4
        for (int p = lane; p < n; p += 64) {
            float2 pt = tilev[p];
            float dx = qx - pt.x, dy = qy - pt.y;
            float d2 = fmaf(dx, dx, dy * dy);
            if (d2 < thr) {
                int pos = atomicAdd(&cnt[w], 1);
                if (pos < CAP2) ci[w][pos] = base + p;
            }
        }
    }
    __syncthreads();

    // ---- pass 3: exact float64 rank among candidates, ties -> lower index ----
    const int C = min(cnt[w], CAP2);
    for (int c = lane; c < C; c += 64) {
        int idx = ci[w][c];
        double dx = (double)qx - (double)ts[idx * 2];
        double dy = (double)qy - (double)ts[idx * 2 + 1];
        chd[w][c] = dx * dx + dy * dy;
    }
    __syncthreads();
    for (int c = lane; c < C; c += 64) {
        double key = chd[w][c];
        int   idx = ci[w][c];
        int rank = 0;
        for (int o = 0; o < C; o++) {
            double ok = chd[w][o];
            int    oi = ci[w][o];
            rank += ((ok < key) || (ok == key && oi < idx)) ? 1 : 0;
        }
        if (rank < KNN) nb[q * KNN + rank] = idx;
    }
}

// ---------------------------------------------------------------------------
// Fused graph build + 3-layer GCN + head. 2 graphs (64 rows) per block,
// 512 threads / 8 waves; each wave owns 32 output cols and computes BOTH
// graphs -> every W fragment load feeds 2 MFMAs (halves W L2 traffic).
// fp16 hi/lo split MFMA; T^T in registers (shfl_xor half-exchange).
// LDS = X(hi/lo, 64 rows) + Ahat(2 graphs): 81,152 B -> 2 blocks/CU.
// ---------------------------------------------------------------------------
#define PX 276   // X/H row pitch in fp16 (552B stride -> 2-way-free b64 reads)
#define PT 36    // Ahat row pitch in fp16

__device__ inline half8 ld_h8(const _Float16* p) {   // LDS, 8B aligned
    union { half8 h; uint2 u[2]; } r;
    r.u[0] = *reinterpret_cast<const uint2*>(p);
    r.u[1] = *reinterpret_cast<const uint2*>(p + 4);
    return r.h;
}
__device__ inline half8 ld_h8_g(const _Float16* p) { // global, 16B aligned
    union { half8 h; uint4 u; } r;
    r.u = *reinterpret_cast<const uint4*>(p);
    return r.h;
}
__device__ inline f32x16 zero16() {
    f32x16 z;
#pragma unroll
    for (int i = 0; i < 16; i++) z[i] = 0.f;
    return z;
}
__device__ inline unsigned pk_u(float a, float b) {   // packed f16 (RTZ), 1 inst
    union { fp16x2 v; unsigned u; } c;
    c.v = __builtin_amdgcn_cvt_pkrtz(a, b);
    return c.u;
}
__device__ inline float f16lo(unsigned u) {
    union { unsigned u; fp16x2 v; } c; c.u = u; return (float)c.v[0];
}
__device__ inline float f16hi(unsigned u) {
    union { unsigned u; fp16x2 v; } c; c.u = u; return (float)c.v[1];
}
// Build apply A-fragment (nodes 16*ks2 + 8h + j) from register-resident packed
// T^T words w[8] (word g = slots 2g,2g+1; slot r holds node (r&3)+8(r>>2)+4h).
__device__ inline half8 frag_x(const unsigned* w, int ks2, int h) {
    unsigned w0 = w[4 * ks2 + 0], w1 = w[4 * ks2 + 1];
    unsigned w2 = w[4 * ks2 + 2], w3 = w[4 * ks2 + 3];
    unsigned sA = h ? w0 : w2, sB = h ? w1 : w3;      // what partner needs
    unsigned rA = __shfl_xor(sA, 32);
    unsigned rB = __shfl_xor(sB, 32);
    unsigned kA = h ? w2 : w0, kB = h ? w3 : w1;      // what we keep
    union { half8 h8; unsigned u[4]; } f;
    f.u[0] = h ? rA : kA;
    f.u[1] = h ? rB : kB;
    f.u[2] = h ? kA : rA;
    f.u[3] = h ? kB : rB;
    return f.h8;
}
#define MFMA(a, b, c) __builtin_amdgcn_mfma_f32_32x32x16_f16((a), (b), (c), 0, 0, 0)

__global__ __launch_bounds__(512, 4) void gcn_k(
    const float* __restrict__ qs, const float* __restrict__ qf,
    const float* __restrict__ ts, const float* __restrict__ tf,
    const float* __restrict__ ty, const float* __restrict__ Wout,
    const int* __restrict__ nb,
    const _Float16* __restrict__ W0hi, const _Float16* __restrict__ W0lo,
    const _Float16* __restrict__ W1hi, const _Float16* __restrict__ W1lo,
    const _Float16* __restrict__ W2hi, const _Float16* __restrict__ W2lo,
    float* __restrict__ out) {
    __shared__ __align__(16) _Float16 Xhi[64 * PX];   // 35,328 B
    __shared__ __align__(16) _Float16 Xlo[64 * PX];   // 35,328 B
    __shared__ _Float16 Ahhi[2 * 32 * PT];            //  4,608 B
    __shared__ _Float16 Ahlo[2 * 32 * PT];            //  4,608 B
    __shared__ float coords[128];
    __shared__ float dinv[64];
    __shared__ float yvs[64];
    __shared__ int   idxs[64];

    const int t = threadIdx.x;
    const int w = t >> 6, lane = t & 63;
    const int h = lane >> 5, ln = lane & 31;
    const int g2 = blockIdx.x * 2;          // first graph of this block

    // ---- indices, coords, y values (64 nodes = 2 graphs) ----
    if (t < 64) {
        int g = t >> 5, n = t & 31;
        int idx = (n == 0) ? -1 : nb[(g2 + g) * KNN + (n - 1)];
        idxs[t] = idx;
        const float* c = (n == 0) ? (qs + (size_t)(g2 + g) * 2) : (ts + (size_t)idx * 2);
        coords[t * 2 + 0] = c[0];
        coords[t * 2 + 1] = c[1];
        yvs[t] = (n == 0) ? 0.f : ty[idx];
    }
    __syncthreads();

    // ---- build X hi/lo: 64 rows, 8 rows per wave, prefetched gathers ----
    {
        const float* s0 = ((w & 31) == 0) ? (qf + (size_t)(g2 + (w >> 5)) * 256)
                                          : (tf + (size_t)idxs[w] * 256);
        float4 pv = reinterpret_cast<const float4*>(s0)[lane];
        for (int r = w; r < 64; r += 8) {
            float4 cv = pv;
            int rn = r + 8;
            if (rn < 64) {
                const float* sn = ((rn & 31) == 0) ? (qf + (size_t)(g2 + (rn >> 5)) * 256)
                                                   : (tf + (size_t)idxs[rn] * 256);
                pv = reinterpret_cast<const float4*>(sn)[lane];
            }
            float a4[4] = {cv.x, cv.y, cv.z, cv.w};
            unsigned hw[2], lw[2];
#pragma unroll
            for (int j = 0; j < 2; j++) {
                float x0 = a4[2 * j], x1 = a4[2 * j + 1];
                hw[j] = pk_u(x0, x1);
                lw[j] = pk_u((x0 - f16lo(hw[j])) * LO_SCALE,
                             (x1 - f16hi(hw[j])) * LO_SCALE);
            }
            *reinterpret_cast<uint2*>(&Xhi[r * PX + 4 * lane]) = *reinterpret_cast<uint2*>(hw);
            *reinterpret_cast<uint2*>(&Xlo[r * PX + 4 * lane]) = *reinterpret_cast<uint2*>(lw);
            if (lane == 0) {   // K-tail cols 256..271: y, ind, zeros
                float yv = yvs[r];
                _Float16 thi[16], tlo[16];
#pragma unroll
                for (int j = 0; j < 16; j++) { thi[j] = (_Float16)0.f; tlo[j] = (_Float16)0.f; }
                _Float16 yh = (_Float16)yv;
                thi[0] = yh;
                tlo[0] = (_Float16)((yv - (float)yh) * LO_SCALE);
                thi[1] = ((r & 31) == 0) ? (_Float16)1.f : (_Float16)0.f;
#pragma unroll
                for (int c = 0; c < 4; c++) {
                    *reinterpret_cast<uint2*>(&Xhi[r * PX + 256 + 4 * c]) = reinterpret_cast<uint2*>(thi)[c];
                    *reinterpret_cast<uint2*>(&Xlo[r * PX + 256 + 4 * c]) = reinterpret_cast<uint2*>(tlo)[c];
                }
            }
        }
    }

    // ---- Ahat stage 1: row sums -> dinv (128 threads = 2 graphs) ----
    if (t < 128) {
        int g = t >> 6, i = (t >> 1) & 31, jh = t & 1;
        int ni = g * 32 + i;
        float xi = coords[ni * 2], yi = coords[ni * 2 + 1];
        float part = 0.f;
#pragma unroll
        for (int jj = 0; jj < 16; jj++) {
            int nj = g * 32 + jh * 16 + jj;
            float dx = xi - coords[nj * 2], dy = yi - coords[nj * 2 + 1];
            part += __expf(-0.5f * (dx * dx + dy * dy));
        }
        float asum = part + __shfl_xor(part, 1);
        if (jh == 0) dinv[ni] = 1.0f / sqrtf(asum);
    }
    __syncthreads();
    // ---- Ahat stage 2: normalize in fp32, split hi/lo ----
    if (t < 128) {
        int g = t >> 6, i = (t >> 1) & 31, jh = t & 1;
        int ni = g * 32 + i;
        float xi = coords[ni * 2], yi = coords[ni * 2 + 1];
        float di = dinv[ni];
        _Float16 ahi[16], alo[16];
#pragma unroll
        for (int jj = 0; jj < 16; jj++) {
            int nj = g * 32 + jh * 16 + jj;
            float dx = xi - coords[nj * 2], dy = yi - coords[nj * 2 + 1];
            float a = __expf(-0.5f * (dx * dx + dy * dy)) * di * dinv[nj];
            _Float16 hi = (_Float16)a;
            ahi[jj] = hi;
            alo[jj] = (_Float16)((a - (float)hi) * LO_SCALE);
        }
        _Float16* dh = &Ahhi[ni * PT + jh * 16];
        _Float16* dl = &Ahlo[ni * PT + jh * 16];
#pragma unroll
        for (int c = 0; c < 4; c++) {
            reinterpret_cast<uint2*>(dh)[c] = reinterpret_cast<uint2*>(ahi)[c];
            reinterpret_cast<uint2*>(dl)[c] = reinterpret_cast<uint2*>(alo)[c];
        }
    }
    __syncthreads();

    // ---- 3 GCN layers (wave w: cols [32w,32w+32), BOTH graphs) ----
    const _Float16* Whis[3] = {W0hi, W1hi, W2hi};
    const _Float16* Wlos[3] = {W0lo, W1lo, W2lo};
    for (int layer = 0; layer < 3; layer++) {
        const _Float16* Whi = Whis[layer];
        const _Float16* Wlo = Wlos[layer];
        const int KS = (layer == 0) ? 17 : 16;

        f32x16 acc0 = zero16(), cor0 = zero16();   // graph 0
        f32x16 acc1 = zero16(), cor1 = zero16();   // graph 1
        const int boBase = (w * 64 + lane) * 8;
        const _Float16* Xa0 = &Xhi[ln * PX + 8 * h];
        const _Float16* Xb0 = &Xlo[ln * PX + 8 * h];
        const _Float16* Xa1 = &Xhi[(32 + ln) * PX + 8 * h];
        const _Float16* Xb1 = &Xlo[(32 + ln) * PX + 8 * h];
#pragma unroll 2
        for (int ks = 0; ks < KS; ks++) {
            int bo = boBase + ks * 4096;
            half8 Bh = ld_h8_g(Whi + bo);
            half8 Bl = ld_h8_g(Wlo + bo);
            half8 A0h = ld_h8(Xa0 + ks * 16);
            half8 A0l = ld_h8(Xb0 + ks * 16);
            half8 A1h = ld_h8(Xa1 + ks * 16);
            half8 A1l = ld_h8(Xb1 + ks * 16);
            acc0 = MFMA(A0h, Bh, acc0);
            cor0 = MFMA(A0l, Bh, cor0);
            cor0 = MFMA(A0h, Bl, cor0);
            acc1 = MFMA(A1h, Bh, acc1);
            cor1 = MFMA(A1l, Bh, cor1);
            cor1 = MFMA(A1h, Bl, cor1);
        }
        __syncthreads();   // all waves' GEMM X-reads done (X may be overwritten)

        // ---- T^T in registers: pack f16 hi/lo words (pkrtz) ----
        unsigned whi0[8], wlo0[8], whi1[8], wlo1[8];
#pragma unroll
        for (int g = 0; g < 8; g++) {
            float x0 = fmaf(cor0[2 * g],     LO_INV, acc0[2 * g]);
            float x1 = fmaf(cor0[2 * g + 1], LO_INV, acc0[2 * g + 1]);
            unsigned hw = pk_u(x0, x1);
            whi0[g] = hw;
            wlo0[g] = pk_u((x0 - f16lo(hw)) * LO_SCALE, (x1 - f16hi(hw)) * LO_SCALE);
            float y0 = fmaf(cor1[2 * g],     LO_INV, acc1[2 * g]);
            float y1 = fmaf(cor1[2 * g + 1], LO_INV, acc1[2 * g + 1]);
            unsigned hv = pk_u(y0, y1);
            whi1[g] = hv;
            wlo1[g] = pk_u((y0 - f16lo(hv)) * LO_SCALE, (y1 - f16hi(hv)) * LO_SCALE);
        }

        // ---- apply: OUT^T = T^T * Ahat_g (symmetric); T frags via shfl ----
        f32x16 p0 = zero16(), pc0 = zero16();
        f32x16 p1 = zero16(), pc1 = zero16();
#pragma unroll
        for (int ks2 = 0; ks2 < 2; ks2++) {
            half8 bA0h = ld_h8(&Ahhi[ln * PT + ks2 * 16 + 8 * h]);
            half8 bA0l = ld_h8(&Ahlo[ln * PT + ks2 * 16 + 8 * h]);
            half8 bA1h = ld_h8(&Ahhi[(32 + ln) * PT + ks2 * 16 + 8 * h]);
            half8 bA1l = ld_h8(&Ahlo[(32 + ln) * PT + ks2 * 16 + 8 * h]);
            half8 t0hi = frag_x(whi0, ks2, h);
            half8 t0lo = frag_x(wlo0, ks2, h);
            half8 t1hi = frag_x(whi1, ks2, h);
            half8 t1lo = frag_x(wlo1, ks2, h);
            p0  = MFMA(t0hi, bA0h, p0);
            pc0 = MFMA(t0lo, bA0h, pc0);
            pc0 = MFMA(t0hi, bA0l, pc0);
            p1  = MFMA(t1hi, bA1h, p1);
            pc1 = MFMA(t1lo, bA1h, pc1);
            pc1 = MFMA(t1hi, bA1l, pc1);
        }

        // relu + store H hi/lo (row = g*32+ln, feat = 32w + 8c + 4h + m)
#pragma unroll
        for (int g = 0; g < 2; g++) {
            const f32x16& P = g ? p1 : p0;
            const f32x16& C = g ? pc1 : pc0;
            int row = g * 32 + ln;
#pragma unroll
            for (int c = 0; c < 4; c++) {
                float x0 = fmaf(C[4 * c + 0], LO_INV, P[4 * c + 0]);
                float x1 = fmaf(C[4 * c + 1], LO_INV, P[4 * c + 1]);
                float x2 = fmaf(C[4 * c + 2], LO_INV, P[4 * c + 2]);
                float x3 = fmaf(C[4 * c + 3], LO_INV, P[4 * c + 3]);
                x0 = fmaxf(x0, 0.f); x1 = fmaxf(x1, 0.f);
                x2 = fmaxf(x2, 0.f); x3 = fmaxf(x3, 0.f);
                unsigned hw[2], lw[2];
                hw[0] = pk_u(x0, x1);
                hw[1] = pk_u(x2, x3);
                lw[0] = pk_u((x0 - f16lo(hw[0])) * LO_SCALE, (x1 - f16hi(hw[0])) * LO_SCALE);
                lw[1] = pk_u((x2 - f16lo(hw[1])) * LO_SCALE, (x3 - f16hi(hw[1])) * LO_SCALE);
                int feat = 32 * w + 8 * c + 4 * h;
                *reinterpret_cast<uint2*>(&Xhi[row * PX + feat]) = *reinterpret_cast<uint2*>(hw);
                *reinterpret_cast<uint2*>(&Xlo[row * PX + feat]) = *reinterpret_cast<uint2*>(lw);
            }
        }
        __syncthreads();   // H ready
    }

    // ---- head: out[g2+g] = (Hhi + Hlo/1024)[center_g] . Wout, fp32 ----
    if (w < 2) {
        float4 wv = reinterpret_cast<const float4*>(Wout)[lane];
        union { uint2 u; _Float16 f[4]; } hh, hl;
        hh.u = *reinterpret_cast<const uint2*>(&Xhi[(w * 32) * PX + 4 * lane]);
        hl.u = *reinterpret_cast<const uint2*>(&Xlo[(w * 32) * PX + 4 * lane]);
        float s = ((float)hh.f[0] + (float)hl.f[0] * LO_INV) * wv.x
                + ((float)hh.f[1] + (float)hl.f[1] * LO_INV) * wv.y
                + ((float)hh.f[2] + (float)hl.f[2] * LO_INV) * wv.z
                + ((float)hh.f[3] + (float)hl.f[3] * LO_INV) * wv.w;
#pragma unroll
        for (int off = 32; off; off >>= 1) s += __shfl_xor(s, off);
        if (lane == 0) out[g2 + w] = s;
    }
}

// ---------------------------------------------------------------------------
extern "C" void kernel_launch(void* const* d_in, const int* in_sizes, int n_in,
                              void* d_out, int out_size, void* d_ws, size_t ws_size,
                              hipStream_t stream) {
    const float* qs   = (const float*)d_in[0];
    const float* qf   = (const float*)d_in[1];
    const float* ts   = (const float*)d_in[2];
    const float* tf   = (const float*)d_in[3];
    const float* ty   = (const float*)d_in[4];
    const float* W0   = (const float*)d_in[5];
    const float* W1   = (const float*)d_in[6];
    const float* W2   = (const float*)d_in[7];
    const float* Wout = (const float*)d_in[8];
    float* out = (float*)d_out;

    char* ws = (char*)d_ws;
    int*      nb   = (int*)ws;                         // 507,904 B
    _Float16* W0hi = (_Float16*)(ws + 524288);         // 139,264 B
    _Float16* W0lo = (_Float16*)(ws + 663552);         // 139,264 B
    _Float16* W1hi = (_Float16*)(ws + 802816);         // 131,072 B
    _Float16* W1lo = (_Float16*)(ws + 933888);         // 131,072 B
    _Float16* W2hi = (_Float16*)(ws + 1064960);        // 131,072 B
    _Float16* W2lo = (_Float16*)(ws + 1196032);        // 131,072 B

    hipLaunchKernelGGL(prep_weights_k, dim3(98), dim3(256), 0, stream,
                       W0, W1, W2, W0hi, W0lo, W1hi, W1lo, W2hi, W2lo);
    hipLaunchKernelGGL(knn_k, dim3(NQ / QPB2), dim3(256), 0, stream, qs, ts, nb);
    hipLaunchKernelGGL(gcn_k, dim3(NQ / 2), dim3(512), 0, stream,
                       qs, qf, ts, tf, ty, Wout, nb,
                       W0hi, W0lo, W1hi, W1lo, W2hi, W2lo, out);
}